// Round 6
// baseline (794.611 us; speedup 1.0000x reference)
//
#include <hip/hip_runtime.h>
#include <cstdint>
#include <cstddef>

typedef _Float16 f16;
typedef _Float16 f16x8 __attribute__((ext_vector_type(8)));
typedef float f32x4 __attribute__((ext_vector_type(4)));

// ---------------------------------------------------------------------------
// W is stored fragment-tiled for mfma_f32_16x16x32_f16's B operand:
// lane l of a wave holds B[n = nf*16 + (l&15)][k = kb*32 + (l>>4)*8 + j].
// Element (n,k) lives at flat f16 index
//   ((n>>4)*(K/32) + (k>>5))*512 + (((k>>3)&3)*16 + (n&15))*8 + (k&7)
// so a wave loads one fragment as ONE coalesced global_load_dwordx4.
// ---------------------------------------------------------------------------

// Wt tile for coef: k = i*8+g  ->  kb=i>>2, lane=(i&3)*16+(o&15), elem g
template <int I, int O>
__global__ void prep_coef(const float* __restrict__ coef,
                          const float* __restrict__ ssp,
                          f16* __restrict__ Wt) {
  constexpr int K32 = (9 * I) / 32;
  int tid = blockIdx.x * 256 + threadIdx.x;
  if (tid >= I * O) return;
  int i = tid / O, o = tid % O;             // o fastest -> coalesced coef reads
  float s = ssp[tid];
  const float* c = coef + (size_t)tid * 8;
  f16x8 out;
#pragma unroll
  for (int g = 0; g < 8; ++g) out[g] = (f16)(c[g] * s);
  size_t addr = ((size_t)(o >> 4) * K32 + (i >> 2)) * 512 +
                (size_t)(((i & 3) * 16) + (o & 15)) * 8;
  *(f16x8*)(Wt + addr) = out;
}

// Wt tile for base: k = 8I+i -> kb=I/4+(i>>5), lane=((i>>3)&3)*16+(o&15), elem i&7
template <int I, int O>
__global__ void prep_base(const float* __restrict__ sb, f16* __restrict__ Wt) {
  constexpr int K32 = (9 * I) / 32;
  int tid = blockIdx.x * 256 + threadIdx.x;
  if (tid >= (I / 8) * O) return;
  int i8 = tid / O, o = tid % O;            // o fastest -> coalesced writes
  f16x8 out;
#pragma unroll
  for (int s = 0; s < 8; ++s)
    out[s] = (f16)sb[(size_t)(i8 * 8 + s) * O + o];
  size_t addr = ((size_t)(o >> 4) * K32 + (I / 4) + (i8 >> 2)) * 512 +
                (size_t)(((i8 & 3) * 16) + (o & 15)) * 8;
  *(f16x8*)(Wt + addr) = out;
}

// ---------------------------------------------------------------------------
// 8-slot cubic B-spline basis, packed-shift form (verified R6, absmax 0.0625).
// ---------------------------------------------------------------------------
__device__ __forceinline__ f16x8 spline8(float h) {
  float v = __builtin_fmaf(2.5f, h, 5.5f);
  float c = floorf(v);
  float f = v - c;
  float f2 = f * f, f3 = f2 * f;
  float b3 = f3 * (1.f / 6.f);
  float t = 1.f - f;
  float b0 = t * t * t * (1.f / 6.f);
  float b1 = (2.f / 3.f) - f2 + 0.5f * f3;
  float b2 = 1.f - b0 - b1 - b3;
  unsigned int u01 =
      __builtin_bit_cast(unsigned int, __builtin_amdgcn_cvt_pkrtz(b0, b1));
  unsigned int u23 =
      __builtin_bit_cast(unsigned int, __builtin_amdgcn_cvt_pkrtz(b2, b3));
  unsigned long long pk = (unsigned long long)u01 |
                          ((unsigned long long)u23 << 32);
  int ci = (int)c;
  int s = (ci - 3) * 16;                // bit offset of slot c-3
  __uint128_t r = 0;
  if (s >= 0) {
    if (s < 128) r = (__uint128_t)pk << s;
  } else {
    int q = -s;
    if (q < 64) r = (__uint128_t)(pk >> q);
  }
  return __builtin_bit_cast(f16x8, r);
}

// ---------------------------------------------------------------------------
// Fused KAN GEMM, 128(M) x 256(N) tile, BK=64. R12: A-FRAGMENTS COMPUTED
// DIRECTLY IN REGISTERS — no LDS, no barriers, no staging.
//
// Key identity: the mfma_f32_16x16x32_f16 A-fragment for lane l is
// A[row][k0 + chunk*8 .. +7] — 8 CONSECUTIVE k with 8-aligned base. In the
// spline region those are exactly the 8 slots of ONE spline8(H[row][i])
// call (i = k0/8 + chunk); in the silu region, 8 consecutive silu values
// from two f32x4 loads. So each wave computes its own av[] straight from
// H. This deletes the LDS round-trip that R7-R11 all kept (MfmaUtil pinned
// 28-32% across 5 schedules: per-step serial path gen->lgkm->MFMA->barrier
// with the 2 co-resident blocks phase-locked). Now waves are fully
// independent; next-half spline VALU schedules into the MFMA shadow with
// no fences. Spline work duplicated 2x across the block's n-halves:
// VALU/SIMD/step ~1700 cyc < MFMA pipe 2483 cyc -> stays subordinate.
//
// Kept from R8/R11: W fragment-tiled layout + B register pipeline (bvB at
// step head under MFMA0; next bvA under MFMA1), XCD pinning (8 (x,z)
// pairs = wgid%8 = XCD, W slice 2.36 MB/XCD L2-resident, strided split-K),
// setprio around MFMA clusters, atomicAdd split-K epilogue.
// Arithmetic bit-identical to R6-R11 (absmax 0.0625).
// ---------------------------------------------------------------------------
template <int I, int ATOMIC, int NX, int NZ>
__global__ __launch_bounds__(256, 2) void gemm_kan(const float* __restrict__ H,
                                                   const f16* __restrict__ W,
                                                   float* __restrict__ C,
                                                   int N) {
  constexpr int K = 9 * I;
  constexpr int KB = 8 * I;                   // spline/base boundary (mult 64)
  constexpr int K32 = K / 32;
  constexpr int KSTEP = 64 * NZ;              // strided split-K step
  constexpr int NSTEP = K / KSTEP;
  const int t = threadIdx.x;
  const int wg = blockIdx.x;
  const int pr = wg & 7;                      // XCD-pair id (wgid%8 == XCD)
  const int n0 = (pr % NX) * 256;
  const int m0 = (wg >> 3) * 128;
  const int kBeg = (pr / NX) * 64;
  const int w = t >> 6, lane = t & 63;
  const int wm = (w >> 1) * 64, wn = (w & 1) * 128;
  const int lr = lane & 15, lq = lane >> 4;   // A-frag: row=lr, chunk=lq

  f32x4 acc[4][8] = {};

  // Per-fragment H row pointers (rows wm+f*16+lr, f=0..3).
  const float* Hf[4];
#pragma unroll
  for (int f = 0; f < 4; ++f)
    Hf[f] = H + (size_t)(m0 + wm + f * 16 + lr) * I;

  // wave's fragment-tiled W pointer at current k-step (advances by KSTEP)
  const f16* pk = W + ((size_t)((n0 + wn) >> 4) * K32 + (kBeg >> 5)) * 512 +
                  lane * 8;

  // prologue: spline inputs for step 0 (kBeg < KB always: kBeg <= 192)
  float hc[4][2];
  {
    const int i0 = kBeg >> 3;
#pragma unroll
    for (int f = 0; f < 4; ++f)
#pragma unroll
      for (int h = 0; h < 2; ++h)
        hc[f][h] = Hf[f][i0 + h * 4 + lq];
  }
  // first B half (kk=0)
  f16x8 bvA[8];
#pragma unroll
  for (int j = 0; j < 8; ++j)
    bvA[j] = *(const f16x8*)(pk + (size_t)j * K32 * 512);

  for (int s = 0; s < NSTEP; ++s) {
    const int k0 = kBeg + s * KSTEP;

    // B frags for kk=32 of THIS step: latency hides under av-gen + MFMA0.
    f16x8 bvB[8];
#pragma unroll
    for (int j = 0; j < 8; ++j)
      bvB[j] = *(const f16x8*)(pk + (size_t)j * K32 * 512 + 512);

    // prefetch NEXT step's spline inputs (full step of cover)
    const int k0n = k0 + KSTEP;
    const bool nsp = (s + 1 < NSTEP) && (k0n < KB);
    float hn[4][2];
    if (nsp) {
      const int in0 = k0n >> 3;
#pragma unroll
      for (int f = 0; f < 4; ++f)
#pragma unroll
        for (int h = 0; h < 2; ++h)
          hn[f][h] = Hf[f][in0 + h * 4 + lq];
    }

    // av half 0, computed in registers (no LDS)
    f16x8 av[4];
    if (k0 < KB) {
#pragma unroll
      for (int f = 0; f < 4; ++f) av[f] = spline8(hc[f][0]);
    } else {
      const int cc = (k0 - KB) + lq * 8;
#pragma unroll
      for (int f = 0; f < 4; ++f) {
        const f32x4* p = (const f32x4*)(Hf[f] + cc);
        f32x4 a0 = p[0], a1 = p[1];
        f16x8 o;
#pragma unroll
        for (int j = 0; j < 8; ++j) {
          float h = (j < 4) ? a0[j & 3] : a1[j & 3];
          o[j] = (f16)(h / (1.f + __expf(-h)));
        }
        av[f] = o;
      }
    }

    __builtin_amdgcn_s_setprio(1);
#pragma unroll
    for (int i = 0; i < 4; ++i)
#pragma unroll
      for (int j = 0; j < 8; ++j)
        acc[i][j] = __builtin_amdgcn_mfma_f32_16x16x32_f16(av[i], bvA[j],
                                                           acc[i][j], 0, 0, 0);
    __builtin_amdgcn_s_setprio(0);

    // av half 1
    if (k0 < KB) {
#pragma unroll
      for (int f = 0; f < 4; ++f) av[f] = spline8(hc[f][1]);
    } else {
      const int cc = (k0 - KB) + 32 + lq * 8;
#pragma unroll
      for (int f = 0; f < 4; ++f) {
        const f32x4* p = (const f32x4*)(Hf[f] + cc);
        f32x4 a0 = p[0], a1 = p[1];
        f16x8 o;
#pragma unroll
        for (int j = 0; j < 8; ++j) {
          float h = (j < 4) ? a0[j & 3] : a1[j & 3];
          o[j] = (f16)(h / (1.f + __expf(-h)));
        }
        av[f] = o;
      }
    }

    // NEXT step's bv(kk=0): latency hides under MFMA half1.
    pk += (size_t)(KSTEP / 32) * 512;
    if (s + 1 < NSTEP) {
#pragma unroll
      for (int j = 0; j < 8; ++j)
        bvA[j] = *(const f16x8*)(pk + (size_t)j * K32 * 512);
    }

    __builtin_amdgcn_s_setprio(1);
#pragma unroll
    for (int i = 0; i < 4; ++i)
#pragma unroll
      for (int j = 0; j < 8; ++j)
        acc[i][j] = __builtin_amdgcn_mfma_f32_16x16x32_f16(av[i], bvB[j],
                                                           acc[i][j], 0, 0, 0);
    __builtin_amdgcn_s_setprio(0);

    if (nsp) {
#pragma unroll
      for (int f = 0; f < 4; ++f)
#pragma unroll
        for (int h = 0; h < 2; ++h)
          hc[f][h] = hn[f][h];
    }
  }

#pragma unroll
  for (int i = 0; i < 4; ++i) {
#pragma unroll
    for (int j = 0; j < 8; ++j) {
      const int col = n0 + wn + j * 16 + lr;
#pragma unroll
      for (int r = 0; r < 4; ++r) {
        const int row = m0 + wm + i * 16 + lq * 4 + r;
        if (ATOMIC)
          atomicAdd(&C[(size_t)row * N + col], acc[i][j][r]);
        else
          C[(size_t)row * N + col] = acc[i][j][r];
      }
    }
  }
}

// ---------------------------------------------------------------------------
extern "C" void kernel_launch(void* const* d_in, const int* in_sizes, int n_in,
                              void* d_out, int out_size, void* d_ws,
                              size_t ws_size, hipStream_t stream) {
  const float* x     = (const float*)d_in[0];
  const float* coef1 = (const float*)d_in[1];
  const float* sb1   = (const float*)d_in[2];
  const float* ssp1  = (const float*)d_in[3];
  const float* coef2 = (const float*)d_in[4];
  const float* sb2   = (const float*)d_in[5];
  const float* ssp2  = (const float*)d_in[6];

  const int Mtot = 8192;
  const int I1 = 512, O1 = 2048, K1 = I1 * 9;   // 4608
  const int I2 = 2048, O2 = 512, K2 = I2 * 9;   // 18432

  char* ws = (char*)d_ws;
  const size_t szW1 = (size_t)O1 * K1 * sizeof(f16);     // 18.9 MB
  const size_t szW2 = (size_t)O2 * K2 * sizeof(f16);     // 18.9 MB
  const size_t szH  = (size_t)Mtot * O1 * sizeof(float); // 67.1 MB
  if (ws_size < szW1 + szW2 + szH) return;  // cannot run; fail visibly
  f16*   W1 = (f16*)ws;
  f16*   W2 = (f16*)(ws + szW1);
  float* h1 = (float*)(ws + szW1 + szW2);

  // weight prep (fragment-tiled layout)
  {
    int n1 = I1 * O1;
    prep_coef<512, 2048><<<(n1 + 255) / 256, 256, 0, stream>>>(coef1, ssp1, W1);
    prep_base<512, 2048><<<(n1 / 8 + 255) / 256, 256, 0, stream>>>(sb1, W1);
    int n2 = I2 * O2;
    prep_coef<2048, 512><<<(n2 + 255) / 256, 256, 0, stream>>>(coef2, ssp2, W2);
    prep_base<2048, 512><<<(n2 / 8 + 255) / 256, 256, 0, stream>>>(sb2, W2);
  }

  // layer 1: h1 = KanAct(x) @ W1^T — 512 blocks, pair=(x), 2/CU.
  gemm_kan<512, 0, 8, 1><<<dim3(512), 256, 0, stream>>>(x, W1, h1, O1);

  // layer 2: out = KanAct(h1) @ W2^T — strided split-K=4, pair=(x,z).
  (void)hipMemsetAsync(d_out, 0, (size_t)Mtot * O2 * sizeof(float), stream);
  gemm_kan<2048, 1, 2, 4><<<dim3(512), 256, 0, stream>>>(h1, W2,
                                                         (float*)d_out, O2);
}

// Round 7
// 541.822 us; speedup vs baseline: 1.4666x; 1.4666x over previous
//
#include <hip/hip_runtime.h>
#include <cstdint>
#include <cstddef>

typedef _Float16 f16;
typedef _Float16 f16x8 __attribute__((ext_vector_type(8)));
typedef float f32x4 __attribute__((ext_vector_type(4)));
typedef float f32x16 __attribute__((ext_vector_type(16)));

// Raw workgroup barrier WITHOUT the __syncthreads() full-drain semantics.
// Only lgkmcnt is drained (LDS visibility: my ds_writes complete + my
// ds_reads of the buffer about to be overwritten complete). Global loads
// (B-fragments, H prefetch) stay IN FLIGHT across the barrier and are
// waited with compiler-inserted counted vmcnt(N) at first use (T4, m218).
#define BAR_LDS() asm volatile("s_waitcnt lgkmcnt(0)\n\ts_barrier" ::: "memory")

// ---------------------------------------------------------------------------
// R13: W is fragment-tiled for mfma_f32_32x32x16_f16's B operand:
// lane l of a wave holds B[k = kb*16 + (l>>5)*8 + j][n = nf*32 + (l&31)].
// Element (n,k) lives at flat f16 index
//   ((n>>5)*(K/16) + (k>>4))*512 + (((k>>3)&1)*32 + (n&31))*8 + (k&7)
// so a wave loads one fragment as ONE coalesced global_load_dwordx4
// (lane l reads tile_base + l*16 bytes).
// ---------------------------------------------------------------------------

// Wt tile for coef: k = i*8+g -> kb=i>>1, lane=(i&1)*32+(o&31), elem g
template <int I, int O>
__global__ void prep_coef(const float* __restrict__ coef,
                          const float* __restrict__ ssp,
                          f16* __restrict__ Wt) {
  constexpr int K16 = (9 * I) / 16;
  int tid = blockIdx.x * 256 + threadIdx.x;
  if (tid >= I * O) return;
  int i = tid / O, o = tid % O;             // o fastest -> coalesced coef reads
  float s = ssp[tid];
  const float* c = coef + (size_t)tid * 8;
  f16x8 out;
#pragma unroll
  for (int g = 0; g < 8; ++g) out[g] = (f16)(c[g] * s);
  size_t addr = ((size_t)(o >> 5) * K16 + (i >> 1)) * 512 +
                (size_t)(((i & 1) * 32) + (o & 31)) * 8;
  *(f16x8*)(Wt + addr) = out;
}

// Wt tile for base: k = 8I + i8*8 + s -> kb = I/2 + (i8>>1),
// lane = (i8&1)*32 + (o&31), elem s.
template <int I, int O>
__global__ void prep_base(const float* __restrict__ sb, f16* __restrict__ Wt) {
  constexpr int K16 = (9 * I) / 16;
  int tid = blockIdx.x * 256 + threadIdx.x;
  if (tid >= (I / 8) * O) return;
  int i8 = tid / O, o = tid % O;            // o fastest -> coalesced writes
  f16x8 out;
#pragma unroll
  for (int s = 0; s < 8; ++s)
    out[s] = (f16)sb[(size_t)(i8 * 8 + s) * O + o];
  size_t addr = ((size_t)(o >> 5) * K16 + (I / 2) + (i8 >> 1)) * 512 +
                (size_t)(((i8 & 1) * 32) + (o & 31)) * 8;
  *(f16x8*)(Wt + addr) = out;
}

// ---------------------------------------------------------------------------
// 8-slot cubic B-spline basis, packed-shift form (verified R6, absmax 0.0625).
// ---------------------------------------------------------------------------
__device__ __forceinline__ f16x8 spline8(float h) {
  float v = __builtin_fmaf(2.5f, h, 5.5f);
  float c = floorf(v);
  float f = v - c;
  float f2 = f * f, f3 = f2 * f;
  float b3 = f3 * (1.f / 6.f);
  float t = 1.f - f;
  float b0 = t * t * t * (1.f / 6.f);
  float b1 = (2.f / 3.f) - f2 + 0.5f * f3;
  float b2 = 1.f - b0 - b1 - b3;
  unsigned int u01 =
      __builtin_bit_cast(unsigned int, __builtin_amdgcn_cvt_pkrtz(b0, b1));
  unsigned int u23 =
      __builtin_bit_cast(unsigned int, __builtin_amdgcn_cvt_pkrtz(b2, b3));
  unsigned long long pk = (unsigned long long)u01 |
                          ((unsigned long long)u23 << 32);
  int ci = (int)c;
  int s = (ci - 3) * 16;                // bit offset of slot c-3
  __uint128_t r = 0;
  if (s >= 0) {
    if (s < 128) r = (__uint128_t)pk << s;
  } else {
    int q = -s;
    if (q < 64) r = (__uint128_t)(pk >> q);
  }
  return __builtin_bit_cast(f16x8, r);
}

// ---------------------------------------------------------------------------
// Fused KAN GEMM, 128(M) x 256(N) tile, BK=64 — R11 structure (LDS-staged
// A, lgkm-only barriers) with R13 shape change: mfma_f32_32x32x16_f16.
//
// R12 lesson: in-register A-gen destroys H coalescing (16 scattered lines
// per load) + spills -> LDS staging is load-bearing; R11 structure kept.
// R13: 32x32x16 vs 16x16x32: measured ceilings 2382 vs 2075 TF -> matrix
// pipe time -13%; MFMA inst count halves (32/wave/step) -> half the issue
// slots, more room for co-wave VALU/loads. The A-fragment is STILL "8
// consecutive k, 8-aligned" (k = (lane>>5)*8 + j), so genTile, the sA
// swizzled layout, and all H handling are bit-identical to R11. Changes:
// W tiling (32-col x 16-k frags), av indices, acc = f32x16 (2x4 frags =
// 128 AGPR, same), epilogue C/D map (m74/m101: col=lane&31,
// row=(reg&3)+8*(reg>>2)+4*(lane>>5)).
//
// Kept: XCD pinning (8 (x,z) pairs == wgid%8 == XCD, W slice 2.36 MB/XCD
// L2-resident; strided split-K), B register pipeline (bvB at step head
// under MFMA half0; next bvA under MFMA half1), setprio on MFMA clusters.
// ---------------------------------------------------------------------------
template <int I, int ATOMIC, int NX, int NZ>
__global__ __launch_bounds__(256, 2) void gemm_kan(const float* __restrict__ H,
                                                   const f16* __restrict__ W,
                                                   float* __restrict__ C,
                                                   int N) {
  constexpr int K = 9 * I;
  constexpr int KB = 8 * I;                   // spline/base boundary (mult 64)
  constexpr int K16 = K / 16;
  constexpr int KSTEP = 64 * NZ;              // strided split-K step
  constexpr int NSTEP = K / KSTEP;
  __shared__ __align__(16) f16 sA[2 * 128 * 64];  // 32 KB double-buffered
  const int t = threadIdx.x;
  const int wg = blockIdx.x;
  const int pr = wg & 7;                      // XCD-pair id (wgid%8 == XCD)
  const int n0 = (pr % NX) * 256;
  const int m0 = (wg >> 3) * 128;
  const int kBeg = (pr / NX) * 64;
  const int w = t >> 6, lane = t & 63;
  const int wm = (w >> 1) * 64, wn = (w & 1) * 128;
  const int l31 = lane & 31, l1 = lane >> 5;  // 32x32 frag: row=l31, khalf=l1
  const int srow = t >> 3;                    // staging row 0..31 (q adds 32)
  const int j_ = t & 7;                       // chunk col 0..7
  const int js = j_ ^ (srow & 7);             // swizzled chunk col

  f32x16 acc[2][4] = {};
  const float* Hrow = H + (size_t)(m0 + srow) * I;

  float hs[4];

  // Generate the 128x64 A-tile for k-range [kg, kg+64) into buffer wb.
  // (Unchanged from R11 — layout/arithmetic identical.)
  auto genTile = [&](int kg, f16* wb) {
    if (kg < KB) {
#pragma unroll
      for (int q = 0; q < 4; ++q)
        *(f16x8*)&wb[((q * 32 + srow) * 8 + js) * 8] = spline8(hs[q]);
      const int kn = kg + KSTEP;
      if (kn < KB) {
        const int i0n = kn >> 3;
#pragma unroll
        for (int q = 0; q < 4; ++q)
          hs[q] = Hrow[(size_t)(q * 32) * I + i0n + j_];
      }
    } else {
      const int c0 = (kg - KB) + j_ * 8;      // 8 consecutive silu inputs
      f32x4 ha[4][2];
#pragma unroll
      for (int q = 0; q < 4; ++q) {
        const f32x4* p = (const f32x4*)(Hrow + (size_t)(q * 32) * I + c0);
        ha[q][0] = p[0];
        ha[q][1] = p[1];
      }
#pragma unroll
      for (int q = 0; q < 4; ++q) {
        f16x8 o;
#pragma unroll
        for (int s = 0; s < 8; ++s) {
          float h = ha[q][s >> 2][s & 3];
          o[s] = (f16)(h / (1.f + __expf(-h)));
        }
        *(f16x8*)&wb[((q * 32 + srow) * 8 + js) * 8] = o;
      }
    }
  };

  // prologue: prefetch H, preload first B half (k-slices 0,1), gen tile 0
  if (kBeg < KB) {
    const int i0 = kBeg >> 3;
#pragma unroll
    for (int q = 0; q < 4; ++q)
      hs[q] = Hrow[(size_t)(q * 32) * I + i0 + j_];
  }
  // wave's fragment-tiled W pointer at current k-step (advances by KSTEP)
  const f16* pk = W + ((size_t)((n0 + wn) >> 5) * K16 + (kBeg >> 4)) * 512 +
                  lane * 8;
  f16x8 bvA[8];                               // [nf*2+ks], k-slices 0,1
#pragma unroll
  for (int nf = 0; nf < 4; ++nf)
#pragma unroll
    for (int ks = 0; ks < 2; ++ks)
      bvA[nf * 2 + ks] = *(const f16x8*)(pk + ((size_t)nf * K16 + ks) * 512);
  genTile(kBeg, sA);                          // also prefetches hs for next
  BAR_LDS();

  int cur = 0;
  for (int s = 0; s < NSTEP; ++s) {
    const f16* rb = sA + cur * (128 * 64);
    f16* wb = sA + (cur ^ 1) * (128 * 64);

    // B frags k-slices 2,3: latency hides under av0 reads + MFMA half0.
    f16x8 bvB[8];
#pragma unroll
    for (int nf = 0; nf < 4; ++nf)
#pragma unroll
      for (int ks = 0; ks < 2; ++ks)
        bvB[nf * 2 + ks] =
            *(const f16x8*)(pk + ((size_t)nf * K16 + 2 + ks) * 512);

    // av half 0 (k-slices 0,1) from LDS: chunk = KS*2 + l1
    f16x8 av[2][2];
#pragma unroll
    for (int fi = 0; fi < 2; ++fi) {
      const int ra = wm + fi * 32 + l31;
#pragma unroll
      for (int ks = 0; ks < 2; ++ks) {
        const int ch = (ks * 2 + l1) ^ (ra & 7);
        av[fi][ks] = *(const f16x8*)&rb[ra * 64 + ch * 8];
      }
    }

    __builtin_amdgcn_s_setprio(1);
#pragma unroll
    for (int fi = 0; fi < 2; ++fi)
#pragma unroll
      for (int nf = 0; nf < 4; ++nf)
#pragma unroll
        for (int ks = 0; ks < 2; ++ks)
          acc[fi][nf] = __builtin_amdgcn_mfma_f32_32x32x16_f16(
              av[fi][ks], bvA[nf * 2 + ks], acc[fi][nf], 0, 0, 0);
    __builtin_amdgcn_s_setprio(0);

    // av half 1 (k-slices 2,3)
#pragma unroll
    for (int fi = 0; fi < 2; ++fi) {
      const int ra = wm + fi * 32 + l31;
#pragma unroll
      for (int ks = 0; ks < 2; ++ks) {
        const int ch = ((2 + ks) * 2 + l1) ^ (ra & 7);
        av[fi][ks] = *(const f16x8*)&rb[ra * 64 + ch * 8];
      }
    }

    // Generate NEXT tile into the other buffer (independent of MFMA).
    const bool more = (s + 1 < NSTEP);
    if (more) genTile(kBeg + (s + 1) * KSTEP, wb);

    // NEXT step's bv (k-slices 0,1): stays in flight across the barrier.
    pk += (size_t)(KSTEP / 16) * 512;
    if (more) {
#pragma unroll
      for (int nf = 0; nf < 4; ++nf)
#pragma unroll
        for (int ks = 0; ks < 2; ++ks)
          bvA[nf * 2 + ks] =
              *(const f16x8*)(pk + ((size_t)nf * K16 + ks) * 512);
    }

    __builtin_amdgcn_s_setprio(1);
#pragma unroll
    for (int fi = 0; fi < 2; ++fi)
#pragma unroll
      for (int nf = 0; nf < 4; ++nf)
#pragma unroll
        for (int ks = 0; ks < 2; ++ks)
          acc[fi][nf] = __builtin_amdgcn_mfma_f32_32x32x16_f16(
              av[fi][ks], bvB[nf * 2 + ks], acc[fi][nf], 0, 0, 0);
    __builtin_amdgcn_s_setprio(0);

    BAR_LDS();         // lgkm-only drain: wb visible, rb safely reusable
    cur ^= 1;
  }

  // Epilogue: 32x32 C/D map (m74/m101): col = lane&31,
  // row = (r&3) + 8*(r>>2) + 4*(lane>>5).
#pragma unroll
  for (int fi = 0; fi < 2; ++fi) {
#pragma unroll
    for (int nf = 0; nf < 4; ++nf) {
      const int col = n0 + wn + nf * 32 + l31;
#pragma unroll
      for (int r = 0; r < 16; ++r) {
        const int row = m0 + wm + fi * 32 + (r & 3) + 8 * (r >> 2) + 4 * l1;
        if (ATOMIC)
          atomicAdd(&C[(size_t)row * N + col], acc[fi][nf][r]);
        else
          C[(size_t)row * N + col] = acc[fi][nf][r];
      }
    }
  }
}

// ---------------------------------------------------------------------------
extern "C" void kernel_launch(void* const* d_in, const int* in_sizes, int n_in,
                              void* d_out, int out_size, void* d_ws,
                              size_t ws_size, hipStream_t stream) {
  const float* x     = (const float*)d_in[0];
  const float* coef1 = (const float*)d_in[1];
  const float* sb1   = (const float*)d_in[2];
  const float* ssp1  = (const float*)d_in[3];
  const float* coef2 = (const float*)d_in[4];
  const float* sb2   = (const float*)d_in[5];
  const float* ssp2  = (const float*)d_in[6];

  const int Mtot = 8192;
  const int I1 = 512, O1 = 2048, K1 = I1 * 9;   // 4608
  const int I2 = 2048, O2 = 512, K2 = I2 * 9;   // 18432

  char* ws = (char*)d_ws;
  const size_t szW1 = (size_t)O1 * K1 * sizeof(f16);     // 18.9 MB
  const size_t szW2 = (size_t)O2 * K2 * sizeof(f16);     // 18.9 MB
  const size_t szH  = (size_t)Mtot * O1 * sizeof(float); // 67.1 MB
  if (ws_size < szW1 + szW2 + szH) return;  // cannot run; fail visibly
  f16*   W1 = (f16*)ws;
  f16*   W2 = (f16*)(ws + szW1);
  float* h1 = (float*)(ws + szW1 + szW2);

  // weight prep (fragment-tiled layout, 32x32x16 B-operand tiles)
  {
    int n1 = I1 * O1;
    prep_coef<512, 2048><<<(n1 + 255) / 256, 256, 0, stream>>>(coef1, ssp1, W1);
    prep_base<512, 2048><<<(n1 / 8 + 255) / 256, 256, 0, stream>>>(sb1, W1);
    int n2 = I2 * O2;
    prep_coef<2048, 512><<<(n2 + 255) / 256, 256, 0, stream>>>(coef2, ssp2, W2);
    prep_base<2048, 512><<<(n2 / 8 + 255) / 256, 256, 0, stream>>>(sb2, W2);
  }

  // layer 1: h1 = KanAct(x) @ W1^T — 512 blocks, pair=(x), 2/CU.
  gemm_kan<512, 0, 8, 1><<<dim3(512), 256, 0, stream>>>(x, W1, h1, O1);

  // layer 2: out = KanAct(h1) @ W2^T — strided split-K=4, pair=(x,z).
  (void)hipMemsetAsync(d_out, 0, (size_t)Mtot * O2 * sizeof(float), stream);
  gemm_kan<2048, 1, 2, 4><<<dim3(512), 256, 0, stream>>>(h1, W2,
                                                         (float*)d_out, O2);
}